// Round 10
// baseline (104.016 us; speedup 1.0000x reference)
//
#include <hip/hip_runtime.h>
#include <cstdint>

typedef __bf16 bf16;
typedef __bf16 bf16x2 __attribute__((ext_vector_type(2)));
typedef __bf16 bf16x4 __attribute__((ext_vector_type(4)));
typedef __bf16 bf16x8 __attribute__((ext_vector_type(8)));
typedef float f32x4 __attribute__((ext_vector_type(4)));

constexpr int S = 2048, D = 1024, H = 16, HD = 64, B = 2;
constexpr size_t TSZ = (size_t)B * H * S * HD;  // 4 Mi elements

__device__ __forceinline__ f32x4 mfma16(bf16x8 a, bf16x8 b, f32x4 c) {
  return __builtin_amdgcn_mfma_f32_16x16x32_bf16(a, b, c, 0, 0, 0);
}

// async global->LDS, 16B per lane. LDS dest = wave-linear (base + lane*16).
__device__ __forceinline__ void gl_lds16(const bf16* g, bf16* s) {
  __builtin_amdgcn_global_load_lds((__attribute__((address_space(1))) void*)g,
                                   (__attribute__((address_space(3))) void*)s,
                                   16, 0, 0);
}

// ---------------------------------------------------------------------------
// prep (merged): blocks 0..2047 convert x fp32->bf16; blocks 2048..3071
// transpose W [K][N] fp32 -> Wt [z][N][K] bf16 via 64x64 LDS tiles.
// ---------------------------------------------------------------------------
__global__ __launch_bounds__(256) void prep_all(const float* __restrict__ x,
                                                const float* __restrict__ W0,
                                                const float* __restrict__ W1,
                                                const float* __restrict__ W2,
                                                const float* __restrict__ W3,
                                                bf16* __restrict__ xb,
                                                bf16* __restrict__ Wt) {
  __shared__ __align__(16) bf16 Lt[64][68];
  const int bid = blockIdx.x, t = threadIdx.x;
  if (bid < 2048) {
    const size_t i = (size_t)bid * 256 + t;
    const float4 a = ((const float4*)x)[2 * i];
    const float4 b = ((const float4*)x)[2 * i + 1];
    bf16x8 o = {(bf16)a.x, (bf16)a.y, (bf16)a.z, (bf16)a.w,
                (bf16)b.x, (bf16)b.y, (bf16)b.z, (bf16)b.w};
    *(bf16x8*)&xb[i * 8] = o;
    return;
  }
  const int r = bid - 2048;
  const int z = r >> 8, rest = r & 255;
  const float* W = z == 0 ? W0 : z == 1 ? W1 : z == 2 ? W2 : W3;
  const int k0 = (rest & 15) * 64, n0 = (rest >> 4) * 64;
  const int tr = t >> 4, tc = (t & 15) * 4;
#pragma unroll
  for (int p = 0; p < 4; ++p) {
    const int rr = 16 * p + tr;
    const float4 v = *(const float4*)&W[(size_t)(k0 + rr) * D + n0 + tc];
    Lt[tc + 0][rr] = (bf16)v.x;
    Lt[tc + 1][rr] = (bf16)v.y;
    Lt[tc + 2][rr] = (bf16)v.z;
    Lt[tc + 3][rr] = (bf16)v.w;
  }
  __syncthreads();
#pragma unroll
  for (int p = 0; p < 4; ++p) {
    const int n = 16 * p + tr;
    const bf16x4 o = *(const bf16x4*)&Lt[n][tc];
    *(bf16x4*)&Wt[((size_t)z * D + n0 + n) * D + k0 + tc] = o;
  }
}

// ---------------------------------------------------------------------------
// bf16 GEMM, m97 structure: BM=128 x BNT tile, BK=64, 4 waves,
// global_load_lds staging with XOR-preswizzled source, swizzled b128 frags.
// ---------------------------------------------------------------------------
template <int MODE, int BNT>
__global__ __launch_bounds__(256) void gemm_bt(const bf16* __restrict__ A,
                                               const bf16* __restrict__ Bt,
                                               void* __restrict__ Cp) {
  constexpr int K = 1024;
  constexpr int NI = BNT / 32;            // n-frags per wave (4 or 2)
  __shared__ __align__(16) bf16 As[128 * 64];
  __shared__ __align__(16) bf16 Bs[BNT * 64];

  const int bid = blockIdx.x, nwg = gridDim.x;       // nwg % 8 == 0
  const int lg = (bid & 7) * (nwg >> 3) + (bid >> 3);  // XCD-chunked
  const int bm = (lg & 31) * 128;
  const int bn = (lg >> 5) * BNT;

  const int t = threadIdx.x, l = t & 63, w = t >> 6;
  const int c = l & 15, g = l >> 4, cx = c & 7;
  const int lrow = l >> 3;                  // row within 1KB LDS chunk
  const int srcc = ((l & 7) ^ lrow) << 3;   // pre-swizzled source k-offset
  const int wm = (w >> 1) * 64, wn = (w & 1) * (BNT / 2);

  f32x4 acc[4][NI] = {};

  for (int kt = 0; kt < K / 64; ++kt) {
    const int k0 = kt * 64;
    __syncthreads();  // prior compute done before overwrite
#pragma unroll
    for (int i = 0; i < 4; ++i) {
      const int ci = i * 4 + w;         // 1KB chunk id (16 per 128-row tile)
      const int row = ci * 8 + lrow;    // tile row 0..127
      gl_lds16(A + (size_t)(bm + row) * K + k0 + srcc, As + ci * 512 + l * 8);
    }
#pragma unroll
    for (int i = 0; i < BNT / 32; ++i) {
      const int ci = i * 4 + w;         // BNT/8 chunks of 1KB
      const int row = ci * 8 + lrow;
      gl_lds16(Bt + (size_t)(bn + row) * K + k0 + srcc, Bs + ci * 512 + l * 8);
    }
    __syncthreads();  // drains vmcnt

    bf16x8 af[4][2], bfv[NI][2];
#pragma unroll
    for (int mi = 0; mi < 4; ++mi) {
      const int row = wm + mi * 16 + c;  // row&7 == cx
#pragma unroll
      for (int kh = 0; kh < 2; ++kh)
        af[mi][kh] = *(const bf16x8*)&As[row * 64 + (((kh * 4 + g) ^ cx) << 3)];
    }
#pragma unroll
    for (int ni = 0; ni < NI; ++ni) {
      const int row = wn + ni * 16 + c;
#pragma unroll
      for (int kh = 0; kh < 2; ++kh)
        bfv[ni][kh] = *(const bf16x8*)&Bs[row * 64 + (((kh * 4 + g) ^ cx) << 3)];
    }
#pragma unroll
    for (int mi = 0; mi < 4; ++mi)
#pragma unroll
      for (int ni = 0; ni < NI; ++ni) {
        acc[mi][ni] = mfma16(af[mi][0], bfv[ni][0], acc[mi][ni]);
        acc[mi][ni] = mfma16(af[mi][1], bfv[ni][1], acc[mi][ni]);
      }
  }

  // epilogue: C frag row = 4g+r, col = c (verified mapping)
#pragma unroll
  for (int mi = 0; mi < 4; ++mi)
#pragma unroll
    for (int ni = 0; ni < NI; ++ni)
#pragma unroll
      for (int r = 0; r < 4; ++r) {
        const int m = bm + wm + mi * 16 + 4 * g + r;
        const int n = bn + wn + ni * 16 + c;
        const float v = acc[mi][ni][r];
        if constexpr (MODE == 0) {
          const int which = n >> 10, nn = n & 1023;
          const int h = nn >> 6, d = nn & 63;
          const int bb = m >> 11, s = m & 2047;
          ((bf16*)Cp)[which * TSZ + ((((size_t)bb * H + h) * S + s) << 6) + d] =
              (bf16)v;
        } else {
          ((float*)Cp)[(size_t)m * D + n] = v;
        }
      }
}

// ---------------------------------------------------------------------------
// Flash attention v10 = r9 inner loop + SPLIT-KV (r6 decomposition, but with
// __launch_bounds__(256,4) so VGPR/prefetch survive — r6 failed at bounds=6,
// VGPR 40) + IN-REGISTER P via kv-permuted V^T LDS layout.
// V^T row layout: chunk (h,g) holds kv {32h+4g+r, 32h+16+4g+r} — exactly the
// S^T fragment order lane (g,c) owns after swapped QK^T. k-permutation
// invariance of MFMA => pa0={p[0][.],p[1][.]}, pa1={p[2][.],p[3][.]} feed PV
// directly; P LDS round-trip (8 writes + 2 b128 reads + lgkm waits) removed;
// Pb's 8KB LDS freed (16KB total -> all 1536 blocks co-resident).
// Items (48/bh): e<16: qt=31-e half0 [0,ceil((qt+1)/2)); e<32: qt=47-e half1;
// e>=32: qt=47-e single. Max 16 iters (vs 33). Partials (O^T,m,l) -> merge.
// ---------------------------------------------------------------------------
__global__ __launch_bounds__(256, 4) void attn10(const bf16* __restrict__ Q,
                                                 const bf16* __restrict__ Kg,
                                                 const bf16* __restrict__ Vg,
                                                 float* __restrict__ Pp) {
  __shared__ __align__(16) bf16 Ks[64 * 64];
  __shared__ __align__(16) bf16 Vt[64 * 64];      // [vd][kv-permuted]

  const int bid = blockIdx.x;
  const int bh = bid & 31, e = bid >> 5;
  int qt, kvA, kvB, half;
  if (e < 16)      { qt = 31 - e; half = 0; kvA = 0;             kvB = (qt + 2) >> 1; }
  else if (e < 32) { qt = 47 - e; half = 1; kvA = (qt + 2) >> 1; kvB = qt + 1; }
  else             { qt = 47 - e; half = 0; kvA = 0;             kvB = qt + 1; }

  const int t = threadIdx.x, l = t & 63, w = t >> 6;
  const int c = l & 15, g = l >> 4, cx = c & 7;
  const float SC = 0.18033688011112042f;   // (1/8)*log2(e)
  const float THRS = 44.3614195558365f;    // 8 / SC (defer-max threshold)

  const bf16* Kbase = Kg + (size_t)bh * S * HD;
  const bf16* Vbase = Vg + (size_t)bh * S * HD;

  const int q0 = qt * 64;
  const int qglob = q0 + 16 * w + c;
  const bf16* Qrow = Q + ((size_t)bh * S + qglob) * HD;
  const bf16x8 qf0 = *(const bf16x8*)&Qrow[g * 8];
  const bf16x8 qf1 = *(const bf16x8*)&Qrow[32 + g * 8];

  // staging index precompute
  const int kv0 = t >> 3, dg0 = t & 7;          // K chunk 0 (rows 0..31)
  const int kv1 = kv0 + 32;                     // K chunk 1 (rows 32..63)
  const int p2 = t & 31, dgv = t >> 5;          // V transpose mapping
  // kv-permuted V^T placement for pair (2p2, 2p2+1):
  const int hv = p2 >> 4;                        // kv>=32 half
  const int gv = (p2 >> 1) & 3;                  // lane-group chunk
  const int jv = ((p2 >> 3) & 1) * 4 + (p2 & 1) * 2;  // element in chunk
  const int vchunk = (hv << 2) | gv;

  // ---- prologue: load tile kvA into registers ----
  const bf16* K0 = Kbase + (size_t)kvA * 64 * HD;
  const bf16* V0 = Vbase + (size_t)kvA * 64 * HD;
  bf16x8 ka0 = *(const bf16x8*)&K0[kv0 * 64 + dg0 * 8];
  bf16x8 ka1 = *(const bf16x8*)&K0[kv1 * 64 + dg0 * 8];
  bf16x8 va0 = *(const bf16x8*)&V0[(2 * p2) * 64 + dgv * 8];
  bf16x8 va1 = *(const bf16x8*)&V0[(2 * p2 + 1) * 64 + dgv * 8];

  f32x4 oacc[4] = {};
  float mrun = -1e30f, lrun = 0.f;   // lrun: per-lane partial

  for (int kt = kvA; kt < kvB; ++kt) {
    // ---- barrier A: all waves done reading previous tile's LDS ----
    __builtin_amdgcn_s_barrier();
    __builtin_amdgcn_sched_barrier(0);

    // ---- write current regs -> LDS (K swizzled; V kv-permuted) ----
    *(bf16x8*)&Ks[kv0 * 64 + ((dg0 ^ (kv0 & 7)) << 3)] = ka0;
    *(bf16x8*)&Ks[kv1 * 64 + ((dg0 ^ (kv1 & 7)) << 3)] = ka1;
#pragma unroll
    for (int i = 0; i < 8; ++i) {
      const int vd = 8 * dgv + i;  // vd&7 == i
      bf16x2 pr2 = {va0[i], va1[i]};
      *(bf16x2*)&Vt[vd * 64 + ((vchunk ^ i) << 3) + jv] = pr2;
    }
    // ---- issue next tile's loads (stay in flight across barrier B) ----
    bf16x8 kn0 = ka0, kn1 = ka1, vn0 = va0, vn1 = va1;
    if (kt + 1 < kvB) {
      const bf16* Kt = Kbase + (size_t)(kt + 1) * 64 * HD;
      const bf16* Vs = Vbase + (size_t)(kt + 1) * 64 * HD;
      kn0 = *(const bf16x8*)&Kt[kv0 * 64 + dg0 * 8];
      kn1 = *(const bf16x8*)&Kt[kv1 * 64 + dg0 * 8];
      vn0 = *(const bf16x8*)&Vs[(2 * p2) * 64 + dgv * 8];
      vn1 = *(const bf16x8*)&Vs[(2 * p2 + 1) * 64 + dgv * 8];
    }
    // ---- barrier B: LDS writes visible; vmcnt NOT drained ----
    asm volatile("s_waitcnt lgkmcnt(0)" ::: "memory");
    __builtin_amdgcn_s_barrier();
    __builtin_amdgcn_sched_barrier(0);

    // ---- S^T = K Q^T ----
    f32x4 st[4];
    __builtin_amdgcn_s_setprio(1);
#pragma unroll
    for (int ct = 0; ct < 4; ++ct) {
      const int krow = ct * 16 + c;  // krow&7 == cx
      const bf16x8 kf0 = *(const bf16x8*)&Ks[krow * 64 + ((g ^ cx) << 3)];
      const bf16x8 kf1 = *(const bf16x8*)&Ks[krow * 64 + (((4 + g) ^ cx) << 3)];
      f32x4 z = {};
      z = mfma16(kf0, qf0, z);
      st[ct] = mfma16(kf1, qf1, z);
    }
    __builtin_amdgcn_s_setprio(0);

    if (kt == qt) {  // causal mask, diagonal tile only
#pragma unroll
      for (int ct = 0; ct < 4; ++ct)
#pragma unroll
        for (int r = 0; r < 4; ++r)
          if (kt * 64 + ct * 16 + 4 * g + r > qglob) st[ct][r] = -1e30f;
    }

    // ---- in-lane online softmax: tree max, defer-max rescale ----
    float tm[4];
#pragma unroll
    for (int ct = 0; ct < 4; ++ct)
      tm[ct] = fmaxf(fmaxf(st[ct][0], st[ct][1]), fmaxf(st[ct][2], st[ct][3]));
    float mt = fmaxf(fmaxf(tm[0], tm[1]), fmaxf(tm[2], tm[3]));
    mt = fmaxf(mt, __shfl_xor(mt, 16));
    mt = fmaxf(mt, __shfl_xor(mt, 32));
    if (!__all(mt <= mrun + THRS)) {
      const float mnew = fmaxf(mrun, mt);
      const float fac = __builtin_amdgcn_exp2f((mrun - mnew) * SC);
      lrun *= fac;
#pragma unroll
      for (int ct = 0; ct < 4; ++ct)
#pragma unroll
        for (int r = 0; r < 4; ++r) oacc[ct][r] *= fac;
      mrun = mnew;
    }
    float p[4][4];
    float sq[4];
#pragma unroll
    for (int ct = 0; ct < 4; ++ct) {
#pragma unroll
      for (int r = 0; r < 4; ++r)
        p[ct][r] = __builtin_amdgcn_exp2f((st[ct][r] - mrun) * SC);
      sq[ct] = (p[ct][0] + p[ct][1]) + (p[ct][2] + p[ct][3]);
    }
    lrun += (sq[0] + sq[1]) + (sq[2] + sq[3]);

    // ---- P in-register (B-frag slot k=8g+j <-> kv 32h+16(j>=4)+4g+(j&3)) ----
    const bf16x8 pa0 = {(bf16)p[0][0], (bf16)p[0][1], (bf16)p[0][2], (bf16)p[0][3],
                        (bf16)p[1][0], (bf16)p[1][1], (bf16)p[1][2], (bf16)p[1][3]};
    const bf16x8 pa1 = {(bf16)p[2][0], (bf16)p[2][1], (bf16)p[2][2], (bf16)p[2][3],
                        (bf16)p[3][0], (bf16)p[3][1], (bf16)p[3][2], (bf16)p[3][3]};

    // ---- O^T += V^T P^T (V^T read in the same kv permutation) ----
    __builtin_amdgcn_s_setprio(1);
#pragma unroll
    for (int ct = 0; ct < 4; ++ct) {
      const int vrow = ct * 16 + c;
      const bf16x8 vt0 = *(const bf16x8*)&Vt[vrow * 64 + ((g ^ cx) << 3)];
      const bf16x8 vt1 = *(const bf16x8*)&Vt[vrow * 64 + (((4 + g) ^ cx) << 3)];
      oacc[ct] = mfma16(vt0, pa0, oacc[ct]);
      oacc[ct] = mfma16(vt1, pa1, oacc[ct]);
    }
    __builtin_amdgcn_s_setprio(0);

    ka0 = kn0; ka1 = kn1; va0 = vn0; va1 = vn1;
  }

  // ---- epilogue: reduce l, write raw partial (O^T, m, l) f32 ----
  float lt = lrun;
  lt += __shfl_xor(lt, 16);
  lt += __shfl_xor(lt, 32);
  // row record: [64 O values][m][l][pad2] = 68 f32
  float* Pr = Pp + ((((size_t)bh * 32 + qt) * 2 + half) * 64 + 16 * w + c) * 68;
#pragma unroll
  for (int ct = 0; ct < 4; ++ct)
    *(f32x4*)&Pr[16 * ct + 4 * g] = oacc[ct];
  if (g == 0) { Pr[64] = mrun; Pr[65] = lt; }
}

// ---------------------------------------------------------------------------
// Merge split-kv partials -> Ab [B,S,D] bf16. One wave per (bh, s) row.
// ---------------------------------------------------------------------------
__global__ __launch_bounds__(256) void attn_merge(const float* __restrict__ Pp,
                                                  bf16* __restrict__ Ab) {
  const float SC = 0.18033688011112042f;
  const int gid = blockIdx.x * 4 + (threadIdx.x >> 6);  // 0..65535
  const int bh = gid >> 11, s = gid & 2047;
  const int lane = threadIdx.x & 63;
  const int qt = s >> 6, row = s & 63;
  const float* r0 = Pp + ((((size_t)bh * 32 + qt) * 2 + 0) * 64 + row) * 68;
  float o = r0[lane];
  float m = r0[64], l = r0[65];
  if (qt >= 16) {  // combine half1
    const float* r1 = r0 + 64 * 68;
    const float o1 = r1[lane], m1 = r1[64], l1 = r1[65];
    const float mn = fmaxf(m, m1);
    const float f0 = exp2f((m - mn) * SC), f1 = exp2f((m1 - mn) * SC);
    o = o * f0 + o1 * f1;
    l = l * f0 + l1 * f1;
  }
  const int bb = bh >> 4, h = bh & 15;
  Ab[((size_t)bb * S + s) * D + h * 64 + lane] = (bf16)(o / l);
}

// ---------------------------------------------------------------------------
extern "C" void kernel_launch(void* const* d_in, const int* in_sizes, int n_in,
                              void* d_out, int out_size, void* d_ws, size_t ws_size,
                              hipStream_t stream) {
  const float* x  = (const float*)d_in[0];
  const float* Wq = (const float*)d_in[1];
  const float* Wk = (const float*)d_in[2];
  const float* Wv = (const float*)d_in[3];
  const float* Wo = (const float*)d_in[4];
  float* out = (float*)d_out;

  bf16* xb  = (bf16*)d_ws;                       // 4Mi  (8 MB)
  bf16* Wt  = xb + (size_t)B * S * D;            // 4Mi  (8 MB) [4][1024][1024]
  bf16* QKV = Wt + (size_t)4 * D * D;            // 12Mi (24 MB) [3][B,H,S,Dh]
  bf16* Ab  = QKV + 3 * TSZ;                     // 4Mi  (8 MB) [B*S][D]
  float* Pp = (float*)(Ab + TSZ);                // 32*32*2*64*68 f32 (35.7 MB)

  prep_all<<<3072, 256, 0, stream>>>(x, Wq, Wk, Wv, Wo, xb, Wt);
  gemm_bt<0, 128><<<768, 256, 0, stream>>>(xb, Wt, QKV);             // fused QKV
  attn10<<<1536, 256, 0, stream>>>(QKV, QKV + TSZ, QKV + 2 * TSZ, Pp);
  attn_merge<<<16384, 256, 0, stream>>>(Pp, Ab);
  gemm_bt<1, 64><<<512, 256, 0, stream>>>(Ab, Wt + (size_t)3 * D * D, out);
}

// Round 11
// 98.565 us; speedup vs baseline: 1.0553x; 1.0553x over previous
//
#include <hip/hip_runtime.h>
#include <cstdint>

typedef __bf16 bf16;
typedef __bf16 bf16x2 __attribute__((ext_vector_type(2)));
typedef __bf16 bf16x4 __attribute__((ext_vector_type(4)));
typedef __bf16 bf16x8 __attribute__((ext_vector_type(8)));
typedef float f32x4 __attribute__((ext_vector_type(4)));

constexpr int S = 2048, D = 1024, H = 16, HD = 64, B = 2;
constexpr size_t TSZ = (size_t)B * H * S * HD;  // 4 Mi elements

__device__ __forceinline__ f32x4 mfma16(bf16x8 a, bf16x8 b, f32x4 c) {
  return __builtin_amdgcn_mfma_f32_16x16x32_bf16(a, b, c, 0, 0, 0);
}

// async global->LDS, 16B per lane. LDS dest = wave-linear (base + lane*16).
__device__ __forceinline__ void gl_lds16(const bf16* g, bf16* s) {
  __builtin_amdgcn_global_load_lds((__attribute__((address_space(1))) void*)g,
                                   (__attribute__((address_space(3))) void*)s,
                                   16, 0, 0);
}

// ---------------------------------------------------------------------------
// prep (merged): blocks 0..2047 convert x fp32->bf16; blocks 2048..3071
// transpose W [K][N] fp32 -> Wt [z][N][K] bf16 via 64x64 LDS tiles.
// ---------------------------------------------------------------------------
__global__ __launch_bounds__(256) void prep_all(const float* __restrict__ x,
                                                const float* __restrict__ W0,
                                                const float* __restrict__ W1,
                                                const float* __restrict__ W2,
                                                const float* __restrict__ W3,
                                                bf16* __restrict__ xb,
                                                bf16* __restrict__ Wt) {
  __shared__ __align__(16) bf16 Lt[64][68];
  const int bid = blockIdx.x, t = threadIdx.x;
  if (bid < 2048) {
    const size_t i = (size_t)bid * 256 + t;
    const float4 a = ((const float4*)x)[2 * i];
    const float4 b = ((const float4*)x)[2 * i + 1];
    bf16x8 o = {(bf16)a.x, (bf16)a.y, (bf16)a.z, (bf16)a.w,
                (bf16)b.x, (bf16)b.y, (bf16)b.z, (bf16)b.w};
    *(bf16x8*)&xb[i * 8] = o;
    return;
  }
  const int r = bid - 2048;
  const int z = r >> 8, rest = r & 255;
  const float* W = z == 0 ? W0 : z == 1 ? W1 : z == 2 ? W2 : W3;
  const int k0 = (rest & 15) * 64, n0 = (rest >> 4) * 64;
  const int tr = t >> 4, tc = (t & 15) * 4;
#pragma unroll
  for (int p = 0; p < 4; ++p) {
    const int rr = 16 * p + tr;
    const float4 v = *(const float4*)&W[(size_t)(k0 + rr) * D + n0 + tc];
    Lt[tc + 0][rr] = (bf16)v.x;
    Lt[tc + 1][rr] = (bf16)v.y;
    Lt[tc + 2][rr] = (bf16)v.z;
    Lt[tc + 3][rr] = (bf16)v.w;
  }
  __syncthreads();
#pragma unroll
  for (int p = 0; p < 4; ++p) {
    const int n = 16 * p + tr;
    const bf16x4 o = *(const bf16x4*)&Lt[n][tc];
    *(bf16x4*)&Wt[((size_t)z * D + n0 + n) * D + k0 + tc] = o;
  }
}

// ---------------------------------------------------------------------------
// bf16 GEMM, m97 structure: BM=128 x BNT tile, BK=64, 4 waves,
// global_load_lds staging with XOR-preswizzled source, swizzled b128 frags.
// ---------------------------------------------------------------------------
template <int MODE, int BNT>
__global__ __launch_bounds__(256) void gemm_bt(const bf16* __restrict__ A,
                                               const bf16* __restrict__ Bt,
                                               void* __restrict__ Cp) {
  constexpr int K = 1024;
  constexpr int NI = BNT / 32;            // n-frags per wave (4 or 2)
  __shared__ __align__(16) bf16 As[128 * 64];
  __shared__ __align__(16) bf16 Bs[BNT * 64];

  const int bid = blockIdx.x, nwg = gridDim.x;       // nwg % 8 == 0
  const int lg = (bid & 7) * (nwg >> 3) + (bid >> 3);  // XCD-chunked
  const int bm = (lg & 31) * 128;
  const int bn = (lg >> 5) * BNT;

  const int t = threadIdx.x, l = t & 63, w = t >> 6;
  const int c = l & 15, g = l >> 4, cx = c & 7;
  const int lrow = l >> 3;                  // row within 1KB LDS chunk
  const int srcc = ((l & 7) ^ lrow) << 3;   // pre-swizzled source k-offset
  const int wm = (w >> 1) * 64, wn = (w & 1) * (BNT / 2);

  f32x4 acc[4][NI] = {};

  for (int kt = 0; kt < K / 64; ++kt) {
    const int k0 = kt * 64;
    __syncthreads();  // prior compute done before overwrite
#pragma unroll
    for (int i = 0; i < 4; ++i) {
      const int ci = i * 4 + w;         // 1KB chunk id (16 per 128-row tile)
      const int row = ci * 8 + lrow;    // tile row 0..127
      gl_lds16(A + (size_t)(bm + row) * K + k0 + srcc, As + ci * 512 + l * 8);
    }
#pragma unroll
    for (int i = 0; i < BNT / 32; ++i) {
      const int ci = i * 4 + w;         // BNT/8 chunks of 1KB
      const int row = ci * 8 + lrow;
      gl_lds16(Bt + (size_t)(bn + row) * K + k0 + srcc, Bs + ci * 512 + l * 8);
    }
    __syncthreads();  // drains vmcnt

    bf16x8 af[4][2], bfv[NI][2];
#pragma unroll
    for (int mi = 0; mi < 4; ++mi) {
      const int row = wm + mi * 16 + c;  // row&7 == cx
#pragma unroll
      for (int kh = 0; kh < 2; ++kh)
        af[mi][kh] = *(const bf16x8*)&As[row * 64 + (((kh * 4 + g) ^ cx) << 3)];
    }
#pragma unroll
    for (int ni = 0; ni < NI; ++ni) {
      const int row = wn + ni * 16 + c;
#pragma unroll
      for (int kh = 0; kh < 2; ++kh)
        bfv[ni][kh] = *(const bf16x8*)&Bs[row * 64 + (((kh * 4 + g) ^ cx) << 3)];
    }
#pragma unroll
    for (int mi = 0; mi < 4; ++mi)
#pragma unroll
      for (int ni = 0; ni < NI; ++ni) {
        acc[mi][ni] = mfma16(af[mi][0], bfv[ni][0], acc[mi][ni]);
        acc[mi][ni] = mfma16(af[mi][1], bfv[ni][1], acc[mi][ni]);
      }
  }

  // epilogue: C frag row = 4g+r, col = c (verified mapping)
#pragma unroll
  for (int mi = 0; mi < 4; ++mi)
#pragma unroll
    for (int ni = 0; ni < NI; ++ni)
#pragma unroll
      for (int r = 0; r < 4; ++r) {
        const int m = bm + wm + mi * 16 + 4 * g + r;
        const int n = bn + wn + ni * 16 + c;
        const float v = acc[mi][ni][r];
        if constexpr (MODE == 0) {
          const int which = n >> 10, nn = n & 1023;
          const int h = nn >> 6, d = nn & 63;
          const int bb = m >> 11, s = m & 2047;
          ((bf16*)Cp)[which * TSZ + ((((size_t)bb * H + h) * S + s) << 6) + d] =
              (bf16)v;
        } else {
          ((float*)Cp)[(size_t)m * D + n] = v;
        }
      }
}

// ---------------------------------------------------------------------------
// Flash attention v11 = r10 inner loop (in-reg P via kv-permuted V^T, zero
// bank conflicts, counted barriers) + UNIFORM Q-TILE PAIRING, direct output.
// Block handles q-tiles (j, 31-j) sequentially -> exactly 33 kv-iterations
// per block: perfectly balanced, no drain, no split-kv partials, no merge.
// Grid: 512 blocks = 32 bh x 16 pairs; 2 blocks/CU, all resident.
// Theory: kernel is LDS-throughput-bound (~274 LDS-unit cyc per wave-iter);
// uniform load -> runtime ~= total LDS work / CU ~= 30us.
// ---------------------------------------------------------------------------
__global__ __launch_bounds__(256, 4) void attn11(const bf16* __restrict__ Q,
                                                 const bf16* __restrict__ Kg,
                                                 const bf16* __restrict__ Vg,
                                                 bf16* __restrict__ O) {
  __shared__ __align__(16) bf16 Ks[64 * 64];
  __shared__ __align__(16) bf16 Vt[64 * 64];      // [vd][kv-permuted]

  const int bid = blockIdx.x;
  const int bh = bid & 31, j = bid >> 5;          // j in 0..15
  const int t = threadIdx.x, l = t & 63, w = t >> 6;
  const int c = l & 15, g = l >> 4, cx = c & 7;
  const int bb = bh >> 4, h = bh & 15;
  const float SC = 0.18033688011112042f;   // (1/8)*log2(e)
  const float THRS = 44.3614195558365f;    // 8 / SC (defer-max threshold)

  const bf16* Kbase = Kg + (size_t)bh * S * HD;
  const bf16* Vbase = Vg + (size_t)bh * S * HD;

  // staging index precompute
  const int kv0 = t >> 3, dg0 = t & 7;          // K chunk 0 (rows 0..31)
  const int kv1 = kv0 + 32;                     // K chunk 1 (rows 32..63)
  const int p2 = t & 31, dgv = t >> 5;          // V transpose mapping
  // kv-permuted V^T placement for pair (2p2, 2p2+1):
  const int hv = p2 >> 4;
  const int gv = (p2 >> 1) & 3;
  const int jv = ((p2 >> 3) & 1) * 4 + (p2 & 1) * 2;
  const int vchunk = (hv << 2) | gv;

  for (int ph = 0; ph < 2; ++ph) {
    const int qt = ph ? (31 - j) : j;
    const int q0 = qt * 64;
    const int qglob = q0 + 16 * w + c;
    const bf16* Qrow = Q + ((size_t)bh * S + qglob) * HD;
    const bf16x8 qf0 = *(const bf16x8*)&Qrow[g * 8];
    const bf16x8 qf1 = *(const bf16x8*)&Qrow[32 + g * 8];

    // ---- prologue: load tile 0 into registers ----
    bf16x8 ka0 = *(const bf16x8*)&Kbase[kv0 * 64 + dg0 * 8];
    bf16x8 ka1 = *(const bf16x8*)&Kbase[kv1 * 64 + dg0 * 8];
    bf16x8 va0 = *(const bf16x8*)&Vbase[(2 * p2) * 64 + dgv * 8];
    bf16x8 va1 = *(const bf16x8*)&Vbase[(2 * p2 + 1) * 64 + dgv * 8];

    f32x4 oacc[4] = {};
    float mrun = -1e30f, lrun = 0.f;   // lrun: per-lane partial

    for (int kt = 0; kt <= qt; ++kt) {
      // ---- barrier A: all waves done reading previous tile's LDS ----
      __builtin_amdgcn_s_barrier();
      __builtin_amdgcn_sched_barrier(0);

      // ---- write current regs -> LDS (K swizzled; V kv-permuted) ----
      *(bf16x8*)&Ks[kv0 * 64 + ((dg0 ^ (kv0 & 7)) << 3)] = ka0;
      *(bf16x8*)&Ks[kv1 * 64 + ((dg0 ^ (kv1 & 7)) << 3)] = ka1;
#pragma unroll
      for (int i = 0; i < 8; ++i) {
        bf16x2 pr2 = {va0[i], va1[i]};
        *(bf16x2*)&Vt[(8 * dgv + i) * 64 + ((vchunk ^ i) << 3) + jv] = pr2;
      }
      // ---- issue next tile's loads (stay in flight across barrier B) ----
      bf16x8 kn0 = ka0, kn1 = ka1, vn0 = va0, vn1 = va1;
      if (kt < qt) {
        const bf16* Kt = Kbase + (size_t)(kt + 1) * 64 * HD;
        const bf16* Vs = Vbase + (size_t)(kt + 1) * 64 * HD;
        kn0 = *(const bf16x8*)&Kt[kv0 * 64 + dg0 * 8];
        kn1 = *(const bf16x8*)&Kt[kv1 * 64 + dg0 * 8];
        vn0 = *(const bf16x8*)&Vs[(2 * p2) * 64 + dgv * 8];
        vn1 = *(const bf16x8*)&Vs[(2 * p2 + 1) * 64 + dgv * 8];
      }
      // ---- barrier B: LDS writes visible; vmcnt NOT drained ----
      asm volatile("s_waitcnt lgkmcnt(0)" ::: "memory");
      __builtin_amdgcn_s_barrier();
      __builtin_amdgcn_sched_barrier(0);

      // ---- S^T = K Q^T ----
      f32x4 st[4];
      __builtin_amdgcn_s_setprio(1);
#pragma unroll
      for (int ct = 0; ct < 4; ++ct) {
        const int krow = ct * 16 + c;  // krow&7 == cx
        const bf16x8 kf0 = *(const bf16x8*)&Ks[krow * 64 + ((g ^ cx) << 3)];
        const bf16x8 kf1 = *(const bf16x8*)&Ks[krow * 64 + (((4 + g) ^ cx) << 3)];
        f32x4 z = {};
        z = mfma16(kf0, qf0, z);
        st[ct] = mfma16(kf1, qf1, z);
      }
      __builtin_amdgcn_s_setprio(0);

      if (kt == qt) {  // causal mask, diagonal tile only
#pragma unroll
        for (int ct = 0; ct < 4; ++ct)
#pragma unroll
          for (int r = 0; r < 4; ++r)
            if (kt * 64 + ct * 16 + 4 * g + r > qglob) st[ct][r] = -1e30f;
      }

      // ---- in-lane online softmax: tree max, defer-max rescale ----
      float tm[4];
#pragma unroll
      for (int ct = 0; ct < 4; ++ct)
        tm[ct] = fmaxf(fmaxf(st[ct][0], st[ct][1]), fmaxf(st[ct][2], st[ct][3]));
      float mt = fmaxf(fmaxf(tm[0], tm[1]), fmaxf(tm[2], tm[3]));
      mt = fmaxf(mt, __shfl_xor(mt, 16));
      mt = fmaxf(mt, __shfl_xor(mt, 32));
      if (!__all(mt <= mrun + THRS)) {
        const float mnew = fmaxf(mrun, mt);
        const float fac = __builtin_amdgcn_exp2f((mrun - mnew) * SC);
        lrun *= fac;
#pragma unroll
        for (int ct = 0; ct < 4; ++ct)
#pragma unroll
          for (int r = 0; r < 4; ++r) oacc[ct][r] *= fac;
        mrun = mnew;
      }
      float p[4][4];
      float sq[4];
#pragma unroll
      for (int ct = 0; ct < 4; ++ct) {
#pragma unroll
        for (int r = 0; r < 4; ++r)
          p[ct][r] = __builtin_amdgcn_exp2f((st[ct][r] - mrun) * SC);
        sq[ct] = (p[ct][0] + p[ct][1]) + (p[ct][2] + p[ct][3]);
      }
      lrun += (sq[0] + sq[1]) + (sq[2] + sq[3]);

      // ---- P in-register (slot k=8g+j <-> kv 32h+16(j>=4)+4g+(j&3)) ----
      const bf16x8 pa0 = {(bf16)p[0][0], (bf16)p[0][1], (bf16)p[0][2], (bf16)p[0][3],
                          (bf16)p[1][0], (bf16)p[1][1], (bf16)p[1][2], (bf16)p[1][3]};
      const bf16x8 pa1 = {(bf16)p[2][0], (bf16)p[2][1], (bf16)p[2][2], (bf16)p[2][3],
                          (bf16)p[3][0], (bf16)p[3][1], (bf16)p[3][2], (bf16)p[3][3]};

      // ---- O^T += V^T P^T (V^T read in the same kv permutation) ----
      __builtin_amdgcn_s_setprio(1);
#pragma unroll
      for (int ct = 0; ct < 4; ++ct) {
        const int vrow = ct * 16 + c;
        const bf16x8 vt0 = *(const bf16x8*)&Vt[vrow * 64 + ((g ^ cx) << 3)];
        const bf16x8 vt1 = *(const bf16x8*)&Vt[vrow * 64 + (((4 + g) ^ cx) << 3)];
        oacc[ct] = mfma16(vt0, pa0, oacc[ct]);
        oacc[ct] = mfma16(vt1, pa1, oacc[ct]);
      }
      __builtin_amdgcn_s_setprio(0);

      ka0 = kn0; ka1 = kn1; va0 = vn0; va1 = vn1;
    }

    // ---- epilogue: reduce l, normalize, direct bf16 store to [B,S,D] ----
    float lt = lrun;
    lt += __shfl_xor(lt, 16);
    lt += __shfl_xor(lt, 32);
    const float inv = 1.f / lt;
    bf16* Orow = O + ((size_t)bb * S + qglob) * D + h * 64;
#pragma unroll
    for (int ct = 0; ct < 4; ++ct)
#pragma unroll
      for (int pr = 0; pr < 2; ++pr) {
        bf16x2 pk = {(bf16)(oacc[ct][2 * pr] * inv),
                     (bf16)(oacc[ct][2 * pr + 1] * inv)};
        *(bf16x2*)&Orow[ct * 16 + 4 * g + 2 * pr] = pk;
      }
    // next phase's barrier A protects LDS before restaging
  }
}

// ---------------------------------------------------------------------------
extern "C" void kernel_launch(void* const* d_in, const int* in_sizes, int n_in,
                              void* d_out, int out_size, void* d_ws, size_t ws_size,
                              hipStream_t stream) {
  const float* x  = (const float*)d_in[0];
  const float* Wq = (const float*)d_in[1];
  const float* Wk = (const float*)d_in[2];
  const float* Wv = (const float*)d_in[3];
  const float* Wo = (const float*)d_in[4];
  float* out = (float*)d_out;

  bf16* xb  = (bf16*)d_ws;                       // 4Mi  (8 MB)
  bf16* Wt  = xb + (size_t)B * S * D;            // 4Mi  (8 MB) [4][1024][1024]
  bf16* QKV = Wt + (size_t)4 * D * D;            // 12Mi (24 MB) [3][B,H,S,Dh]
  bf16* Ab  = QKV + 3 * TSZ;                     // 4Mi  (8 MB) [B*S][D]

  prep_all<<<3072, 256, 0, stream>>>(x, Wq, Wk, Wv, Wo, xb, Wt);
  gemm_bt<0, 128><<<768, 256, 0, stream>>>(xb, Wt, QKV);             // fused QKV
  attn11<<<512, 256, 0, stream>>>(QKV, QKV + TSZ, QKV + 2 * TSZ, Ab);
  gemm_bt<1, 64><<<512, 256, 0, stream>>>(Ab, Wt + (size_t)3 * D * D, out);
}